// Round 1
// baseline (63.862 us; speedup 1.0000x reference)
//
#include <hip/hip_runtime.h>
#include <math.h>

__device__ __forceinline__ float wave_reduce_sum(float v) {
    #pragma unroll
    for (int off = 32; off > 0; off >>= 1)
        v += __shfl_xor(v, off, 64);
    return v;
}

// Kernel 1: rec[b*H + h] = dot(rnn_state[b,:], W_rec[h,:])
// One wave per output element; lanes split R with float4 loads.
__global__ void rec_kernel(const float* __restrict__ rnn,
                           const float* __restrict__ Wrec,
                           float* __restrict__ rec,
                           int B, int H, int R) {
    int w    = (blockIdx.x * blockDim.x + threadIdx.x) >> 6;
    int lane = threadIdx.x & 63;
    int nOut = B * H;
    if (w >= nOut) return;
    int b = w / H;
    int h = w - b * H;
    const float* xr = rnn  + (size_t)b * R;
    const float* wr = Wrec + (size_t)h * R;
    float acc = 0.f;
    for (int r = lane * 4; r < R; r += 256) {
        float4 a = *(const float4*)(xr + r);
        float4 c = *(const float4*)(wr + r);
        acc += a.x * c.x + a.y * c.y + a.z * c.z + a.w * c.w;
    }
    acc = wave_reduce_sum(acc);
    if (lane == 0) rec[w] = acc;
}

// fast tanh: tanh(x) = 1 - 2/(exp(2x)+1); exp via v_exp, recip via v_rcp
__device__ __forceinline__ float fast_tanh(float x) {
    float e = __expf(2.0f * x);
    return 1.0f - 2.0f * __builtin_amdgcn_rcpf(e + 1.0f);
}

// Kernel 2: one wave per (t,b) row. scores[t*B+b] = sum_h tanh(enc+rec)*w + b0 + mask
// Writes scores directly into d_out (same (T,B) layout).
__global__ void score_kernel(const float* __restrict__ enc,
                             const float* __restrict__ mask,
                             const float* __restrict__ rec,
                             const float* __restrict__ wsc,
                             const float* __restrict__ bsc,
                             float* __restrict__ scores,
                             int TB, int B, int H) {
    int w    = (blockIdx.x * blockDim.x + threadIdx.x) >> 6;
    int lane = threadIdx.x & 63;
    if (w >= TB) return;
    int b = w % B;
    const float* er = enc + (size_t)w * H;
    const float* rr = rec + (size_t)b * H;
    float acc = 0.f;
    for (int h = lane * 4; h < H; h += 256) {
        float4 e  = *(const float4*)(er + h);
        float4 rv = *(const float4*)(rr + h);
        float4 wv = *(const float4*)(wsc + h);
        acc += wv.x * fast_tanh(e.x + rv.x);
        acc += wv.y * fast_tanh(e.y + rv.y);
        acc += wv.z * fast_tanh(e.z + rv.z);
        acc += wv.w * fast_tanh(e.w + rv.w);
    }
    acc = wave_reduce_sum(acc);
    if (lane == 0) scores[w] = acc + bsc[0] + mask[w];
}

// Kernel 3: softmax over T per column b, in place on d_out ((T,B) layout).
// One block per b; values kept in registers between passes.
__global__ void softmax_kernel(float* __restrict__ out, int T, int B) {
    const int b   = blockIdx.x;
    const int tid = threadIdx.x;
    const int nth = blockDim.x;

    float sv[32];           // supports T/blockDim <= 32 (4096/256 = 16)
    int   n = 0;
    float m = -INFINITY;
    for (int t = tid; t < T; t += nth) {
        float s = out[(size_t)t * B + b];
        sv[n++] = s;
        m = fmaxf(m, s);
    }

    __shared__ float red[8];
    const int wid  = tid >> 6;
    const int lane = tid & 63;
    const int nw   = nth >> 6;

    #pragma unroll
    for (int off = 32; off > 0; off >>= 1)
        m = fmaxf(m, __shfl_xor(m, off, 64));
    if (lane == 0) red[wid] = m;
    __syncthreads();
    if (tid == 0) {
        float mm = red[0];
        for (int i = 1; i < nw; i++) mm = fmaxf(mm, red[i]);
        red[0] = mm;
    }
    __syncthreads();
    m = red[0];

    float sum = 0.f;
    for (int i = 0; i < n; i++) {
        sv[i] = __expf(sv[i] - m);
        sum += sv[i];
    }
    sum = wave_reduce_sum(sum);
    __syncthreads();             // done reading red[0]
    if (lane == 0) red[wid] = sum;
    __syncthreads();
    if (tid == 0) {
        float ss = red[0];
        for (int i = 1; i < nw; i++) ss += red[i];
        red[0] = ss;
    }
    __syncthreads();
    float inv = 1.0f / red[0];

    n = 0;
    for (int t = tid; t < T; t += nth) {
        out[(size_t)t * B + b] = sv[n++] * inv;
    }
}

extern "C" void kernel_launch(void* const* d_in, const int* in_sizes, int n_in,
                              void* d_out, int out_size, void* d_ws, size_t ws_size,
                              hipStream_t stream) {
    const float* enc  = (const float*)d_in[0];  // (T,B,H)
    const float* mask = (const float*)d_in[1];  // (T,B)
    const float* rnn  = (const float*)d_in[2];  // (B,R)
    // d_in[3] = prev_att_weights, unused by the reference
    const float* Wrec = (const float*)d_in[4];  // (H,R)
    const float* wsc  = (const float*)d_in[5];  // (H,)
    const float* bsc  = (const float*)d_in[6];  // (1,)

    const int H = in_sizes[5];
    const int R = in_sizes[4] / H;
    const int B = in_sizes[2] / R;
    const int T = in_sizes[1] / B;
    const int TB = T * B;

    float* rec    = (float*)d_ws;   // B*H floats = 64 KB
    float* scores = (float*)d_out;  // (T,B) in place

    // Kernel 1: B*H outputs, one wave each, 4 waves per 256-thread block
    {
        int nOut   = B * H;
        int blocks = (nOut + 3) / 4;
        rec_kernel<<<blocks, 256, 0, stream>>>(rnn, Wrec, rec, B, H, R);
    }
    // Kernel 2: T*B rows, one wave each
    {
        int blocks = (TB + 3) / 4;
        score_kernel<<<blocks, 256, 0, stream>>>(enc, mask, rec, wsc, bsc,
                                                 scores, TB, B, H);
    }
    // Kernel 3: one block per b
    softmax_kernel<<<B, 256, 0, stream>>>(scores, T, B);
}

// Round 2
// 56.070 us; speedup vs baseline: 1.1390x; 1.1390x over previous
//
#include <hip/hip_runtime.h>
#include <math.h>

__device__ __forceinline__ float wave_reduce_sum(float v) {
    #pragma unroll
    for (int off = 32; off > 0; off >>= 1)
        v += __shfl_xor(v, off, 64);
    return v;
}
__device__ __forceinline__ float wave_reduce_max(float v) {
    #pragma unroll
    for (int off = 32; off > 0; off >>= 1)
        v = fmaxf(v, __shfl_xor(v, off, 64));
    return v;
}

// fast tanh: tanh(x) = 1 - 2/(exp(2x)+1); exp via v_exp, recip via v_rcp
__device__ __forceinline__ float fast_tanh(float x) {
    float e = __expf(2.0f * x);
    return 1.0f - 2.0f * __builtin_amdgcn_rcpf(e + 1.0f);
}

// Kernel 1: rec[b*H + h] = dot(rnn_state[b,:], W_rec[h,:])
// One wave per output element; lanes split R with float4 loads.
__global__ void rec_kernel(const float* __restrict__ rnn,
                           const float* __restrict__ Wrec,
                           float* __restrict__ rec,
                           int B, int H, int R) {
    int w    = (blockIdx.x * blockDim.x + threadIdx.x) >> 6;
    int lane = threadIdx.x & 63;
    int nOut = B * H;
    if (w >= nOut) return;
    int b = w / H;
    int h = w - b * H;
    const float* xr = rnn  + (size_t)b * R;
    const float* wr = Wrec + (size_t)h * R;
    float acc = 0.f;
    for (int r = lane * 4; r < R; r += 256) {
        float4 a = *(const float4*)(xr + r);
        float4 c = *(const float4*)(wr + r);
        acc += a.x * c.x + a.y * c.y + a.z * c.z + a.w * c.w;
    }
    acc = wave_reduce_sum(acc);
    if (lane == 0) rec[w] = acc;
}

// Kernel 2: each wave owns a fixed b and ROWS consecutive t values.
// rec row + w_score are loaded into registers ONCE, then the inner loop is
// two coalesced float4 enc loads per row + tanh math + wave reduce.
// Scores written TRANSPOSED (B,T) into workspace for a coalesced softmax.
#define SCORE_ROWS 16
__global__ void score_kernel(const float* __restrict__ enc,
                             const float* __restrict__ mask,
                             const float* __restrict__ rec,
                             const float* __restrict__ wsc,
                             const float* __restrict__ bsc,
                             float* __restrict__ scores_t,  // (B,T)
                             int T, int B, int H) {
    const int w    = (blockIdx.x * blockDim.x + threadIdx.x) >> 6;
    const int lane = threadIdx.x & 63;
    const int b     = w % B;
    const int tbase = (w / B) * SCORE_ROWS;
    if (tbase >= T) return;

    const int h0 = lane * 4;          // first half: h in [0, H/2)
    const int h1 = (H >> 1) + h0;     // second half

    // per-lane invariant operands (8 floats each), loaded once
    const float* rr = rec + (size_t)b * H;
    float4 r0 = *(const float4*)(rr + h0);
    float4 r1 = *(const float4*)(rr + h1);
    float4 w0 = *(const float4*)(wsc + h0);
    float4 w1 = *(const float4*)(wsc + h1);
    const float bias = bsc[0];

    const float* erow = enc + ((size_t)tbase * B + b) * H;
    const size_t rstride = (size_t)B * H;

    #pragma unroll
    for (int i = 0; i < SCORE_ROWS; ++i) {
        const float* er = erow + (size_t)i * rstride;
        float4 e0 = *(const float4*)(er + h0);
        float4 e1 = *(const float4*)(er + h1);
        float acc;
        acc  = w0.x * fast_tanh(e0.x + r0.x);
        acc += w0.y * fast_tanh(e0.y + r0.y);
        acc += w0.z * fast_tanh(e0.z + r0.z);
        acc += w0.w * fast_tanh(e0.w + r0.w);
        acc += w1.x * fast_tanh(e1.x + r1.x);
        acc += w1.y * fast_tanh(e1.y + r1.y);
        acc += w1.z * fast_tanh(e1.z + r1.z);
        acc += w1.w * fast_tanh(e1.w + r1.w);
        acc = wave_reduce_sum(acc);
        if (lane == 0) {
            const int t = tbase + i;
            scores_t[(size_t)b * T + t] = acc + bias + mask[(size_t)t * B + b];
        }
    }
}

// Kernel 3: softmax over T per column b. One block (1024 threads) per b.
// Coalesced float4 read from (B,T) scores; scattered 4B writes to (T,B) out.
__global__ void softmax_kernel(const float* __restrict__ scores_t,
                               float* __restrict__ out, int T, int B) {
    const int b    = blockIdx.x;
    const int tid  = threadIdx.x;
    const int wid  = tid >> 6;
    const int lane = tid & 63;
    const int nw   = blockDim.x >> 6;

    float4 v = *(const float4*)(scores_t + (size_t)b * T + tid * 4);

    __shared__ float red[16];

    float m = fmaxf(fmaxf(v.x, v.y), fmaxf(v.z, v.w));
    m = wave_reduce_max(m);
    if (lane == 0) red[wid] = m;
    __syncthreads();
    if (tid < 64) {
        float mm = (tid < nw) ? red[tid] : -INFINITY;
        mm = wave_reduce_max(mm);
        if (tid == 0) red[0] = mm;
    }
    __syncthreads();
    m = red[0];
    __syncthreads();                 // everyone has read red[0]

    v.x = __expf(v.x - m);
    v.y = __expf(v.y - m);
    v.z = __expf(v.z - m);
    v.w = __expf(v.w - m);
    float s = (v.x + v.y) + (v.z + v.w);
    s = wave_reduce_sum(s);
    if (lane == 0) red[wid] = s;
    __syncthreads();
    if (tid < 64) {
        float ss = (tid < nw) ? red[tid] : 0.f;
        ss = wave_reduce_sum(ss);
        if (tid == 0) red[0] = ss;
    }
    __syncthreads();
    const float inv = 1.0f / red[0];

    const int t0 = tid * 4;
    out[(size_t)(t0 + 0) * B + b] = v.x * inv;
    out[(size_t)(t0 + 1) * B + b] = v.y * inv;
    out[(size_t)(t0 + 2) * B + b] = v.z * inv;
    out[(size_t)(t0 + 3) * B + b] = v.w * inv;
}

extern "C" void kernel_launch(void* const* d_in, const int* in_sizes, int n_in,
                              void* d_out, int out_size, void* d_ws, size_t ws_size,
                              hipStream_t stream) {
    const float* enc  = (const float*)d_in[0];  // (T,B,H)
    const float* mask = (const float*)d_in[1];  // (T,B)
    const float* rnn  = (const float*)d_in[2];  // (B,R)
    // d_in[3] = prev_att_weights, unused by the reference
    const float* Wrec = (const float*)d_in[4];  // (H,R)
    const float* wsc  = (const float*)d_in[5];  // (H,)
    const float* bsc  = (const float*)d_in[6];  // (1,)

    const int H = in_sizes[5];
    const int R = in_sizes[4] / H;
    const int B = in_sizes[2] / R;
    const int T = in_sizes[1] / B;

    float* rec      = (float*)d_ws;             // B*H floats (64 KB)
    float* scores_t = (float*)d_ws + (size_t)B * H;  // (B,T) floats (512 KB)
    float* out      = (float*)d_out;            // (T,B)

    // Kernel 1: B*H outputs, one wave each, 4 waves per 256-thread block
    {
        int nOut   = B * H;
        int blocks = (nOut + 3) / 4;
        rec_kernel<<<blocks, 256, 0, stream>>>(rnn, Wrec, rec, B, H, R);
    }
    // Kernel 2: one wave per (b, 16-row strip): T*B/16 waves
    {
        int nWaves = (T / SCORE_ROWS) * B;
        int blocks = (nWaves + 3) / 4;
        score_kernel<<<blocks, 256, 0, stream>>>(enc, mask, rec, wsc, bsc,
                                                 scores_t, T, B, H);
    }
    // Kernel 3: one block per b, T/4 threads (T=4096 -> 1024)
    softmax_kernel<<<B, T / 4, 0, stream>>>(scores_t, out, T, B);
}